// Round 9
// baseline (4903.806 us; speedup 1.0000x reference)
//
#include <hip/hip_runtime.h>
#include <cmath>

#define D 160
#define DD (D*D)          // 25600
#define NVOX (D*D*D)
#define BIGV (NVOX + 2)
#define NBINS 4096
#define HALF 16
#define RGRID 800         // rotate-pass blocks = DD/32, also hist partial count
#define CPT 16            // cells per thread in persistent CCL
#define NSLAB 20          // x-slabs of 8 planes
#define BLKSLAB 50        // blocks per slab (50*256*16 = 204800 = 8*160*160)
#define PGRID (NSLAB * BLKSLAB)   // 1000 persistent blocks (<= 4/CU capacity)
#define NSWEEP 16

// ---------------------------------------------------------------------------
// Rotate-pipeline box filter (window 32, 'same'), INT packed path.
// Buffer layout (a,b,c) c-contiguous; filter along c; write out[c*DD+a*D+b]
// -> layout (c,a,b). Three passes return to identity with each axis filtered.
// MODE 0 fuses class-pack from raw data + CCL lab init (original layout).
// cw0 low 16 bits, cw1 high 16 (max 32768, no carry). Int sums order-free.
// ---------------------------------------------------------------------------
template<int MODE>
__global__ __launch_bounds__(256) void box_rot_int_kernel(
    const void* __restrict__ vin, unsigned* __restrict__ out,
    int* __restrict__ lab)
{
    __shared__ unsigned tin[32][161];
    __shared__ unsigned filt[160][33];
    int L0 = blockIdx.x * 32;
    size_t base = (size_t)L0 * D;

    if (MODE == 0) {
        const float4* s4 = (const float4*)((const float*)vin + base);
        int4* lab4 = (int4*)(lab + base);
        for (int i = threadIdx.x; i < 32 * (D / 4); i += 256) {
            float4 v = s4[i];
            int e = i * 4, r = e / D, c = e - r * D;
            int p = (int)base + e;
            int4 lb; float rr;
            rr = rintf(v.x); tin[r][c]   = (rr==0.f) | ((rr==1.f)?0x10000u:0u); lb.x = (rr==1.f)?(p+1):BIGV;
            rr = rintf(v.y); tin[r][c+1] = (rr==0.f) | ((rr==1.f)?0x10000u:0u); lb.y = (rr==1.f)?(p+2):BIGV;
            rr = rintf(v.z); tin[r][c+2] = (rr==0.f) | ((rr==1.f)?0x10000u:0u); lb.z = (rr==1.f)?(p+3):BIGV;
            rr = rintf(v.w); tin[r][c+3] = (rr==0.f) | ((rr==1.f)?0x10000u:0u); lb.w = (rr==1.f)?(p+4):BIGV;
            lab4[i] = lb;
        }
    } else {
        const uint4* s4 = (const uint4*)((const unsigned*)vin + base);
        for (int i = threadIdx.x; i < 32 * (D / 4); i += 256) {
            uint4 v = s4[i];
            int e = i * 4, r = e / D, c = e - r * D;
            tin[r][c] = v.x; tin[r][c+1] = v.y; tin[r][c+2] = v.z; tin[r][c+3] = v.w;
        }
    }
    __syncthreads();

    {
        int r = threadIdx.x & 31, s = threadIdx.x >> 5;
        int i0 = 20 * s;
        const unsigned* ln = tin[r];
        unsigned sum = 0u;
        int jlo = i0 - 16; if (jlo < 0) jlo = 0;
        int jhi = i0 + 15; if (jhi > D - 1) jhi = D - 1;
        for (int j = jlo; j <= jhi; ++j) sum += ln[j];
        #pragma unroll 4
        for (int k = 0; k < 20; ++k) {
            int i = i0 + k;
            filt[i][r] = sum;
            int add = i + 16, rem = i - 16;
            if (add <= D - 1) sum += ln[add];
            if (rem >= 0)     sum -= ln[rem];
        }
    }
    __syncthreads();

    int r = threadIdx.x & 31;
    for (int c = (threadIdx.x >> 5); c < D; c += 8)
        out[(size_t)c * DD + L0 + r] = filt[c][r];
}

// ---------------------------------------------------------------------------
// Rotate box filter, FLOAT path, pass 1: fuses the lsize*valid gather.
// fp order differs from reference cumsum: perturbs only proba (~1e-7 vs
// 2e-2 threshold); candidates are integer-exact.
// ---------------------------------------------------------------------------
__global__ __launch_bounds__(256) void box_rot_f32_g_kernel(
    const int* __restrict__ lab, const int* __restrict__ cnt,
    const unsigned* __restrict__ cwp, float* __restrict__ out)
{
    __shared__ float tin[32][161];
    __shared__ float filt[160][33];
    int L0 = blockIdx.x * 32;
    size_t base = (size_t)L0 * D;

    const int4*  lab4 = (const int4*)(lab + base);
    const uint4* cw4  = (const uint4*)(cwp + base);
    for (int i = threadIdx.x; i < 32 * (D / 4); i += 256) {
        int4 l = lab4[i];
        uint4 cw = cw4[i];
        int e = i * 4, r = e / D, c = e - r * D;
        tin[r][c]   = (l.x != BIGV && (cw.x >> 16) > 100u) ? (float)cnt[l.x] : 0.f;
        tin[r][c+1] = (l.y != BIGV && (cw.y >> 16) > 100u) ? (float)cnt[l.y] : 0.f;
        tin[r][c+2] = (l.z != BIGV && (cw.z >> 16) > 100u) ? (float)cnt[l.z] : 0.f;
        tin[r][c+3] = (l.w != BIGV && (cw.w >> 16) > 100u) ? (float)cnt[l.w] : 0.f;
    }
    __syncthreads();

    {
        int r = threadIdx.x & 31, s = threadIdx.x >> 5;
        int i0 = 20 * s;
        const float* ln = tin[r];
        float sum = 0.f;
        int jlo = i0 - 16; if (jlo < 0) jlo = 0;
        int jhi = i0 + 15; if (jhi > D - 1) jhi = D - 1;
        for (int j = jlo; j <= jhi; ++j) sum += ln[j];
        #pragma unroll 4
        for (int k = 0; k < 20; ++k) {
            int i = i0 + k;
            filt[i][r] = sum;
            int add = i + 16, rem = i - 16;
            if (add <= D - 1) sum += ln[add];
            if (rem >= 0)     sum -= ln[rem];
        }
    }
    __syncthreads();

    int r = threadIdx.x & 31;
    for (int c = (threadIdx.x >> 5); c < D; c += 8)
        out[(size_t)c * DD + L0 + r] = filt[c][r];
}

// plain float middle pass
__global__ __launch_bounds__(256) void box_rot_f32_kernel(
    const float* __restrict__ fin, float* __restrict__ out)
{
    __shared__ float tin[32][161];
    __shared__ float filt[160][33];
    int L0 = blockIdx.x * 32;
    size_t base = (size_t)L0 * D;

    const float4* s4 = (const float4*)(fin + base);
    for (int i = threadIdx.x; i < 32 * (D / 4); i += 256) {
        float4 v = s4[i];
        int e = i * 4, r = e / D, c = e - r * D;
        tin[r][c] = v.x; tin[r][c+1] = v.y; tin[r][c+2] = v.z; tin[r][c+3] = v.w;
    }
    __syncthreads();

    {
        int r = threadIdx.x & 31, s = threadIdx.x >> 5;
        int i0 = 20 * s;
        const float* ln = tin[r];
        float sum = 0.f;
        int jlo = i0 - 16; if (jlo < 0) jlo = 0;
        int jhi = i0 + 15; if (jhi > D - 1) jhi = D - 1;
        for (int j = jlo; j <= jhi; ++j) sum += ln[j];
        #pragma unroll 4
        for (int k = 0; k < 20; ++k) {
            int i = i0 + k;
            filt[i][r] = sum;
            int add = i + 16, rem = i - 16;
            if (add <= D - 1) sum += ln[add];
            if (rem >= 0)     sum -= ln[rem];
        }
    }
    __syncthreads();

    int r = threadIdx.x & 31;
    for (int c = (threadIdx.x >> 5); c < D; c += 8)
        out[(size_t)c * DD + L0 + r] = filt[c][r];
}

// ---------------------------------------------------------------------------
// cs pass 3 fused with finalize: filter along x; compute candidates / bin
// idx / LDS histogram directly (cs never materialized).
// Input layout (y,z,x): line L = y*D+z, elems along x. Output p = x*DD+L.
// ---------------------------------------------------------------------------
__global__ __launch_bounds__(256) void box_rot_fin_kernel(
    const float* __restrict__ fin, const unsigned* __restrict__ cwp,
    float* __restrict__ cand, unsigned short* __restrict__ idxbuf,
    int* __restrict__ partial)
{
    __shared__ float tin[32][161];
    __shared__ float filt[160][33];
    __shared__ int lh[NBINS];
    for (int i = threadIdx.x; i < NBINS; i += 256) lh[i] = 0;

    int L0 = blockIdx.x * 32;
    size_t base = (size_t)L0 * D;
    const float4* s4 = (const float4*)(fin + base);
    for (int i = threadIdx.x; i < 32 * (D / 4); i += 256) {
        float4 v = s4[i];
        int e = i * 4, r = e / D, c = e - r * D;
        tin[r][c] = v.x; tin[r][c+1] = v.y; tin[r][c+2] = v.z; tin[r][c+3] = v.w;
    }
    __syncthreads();

    {
        int r = threadIdx.x & 31, s = threadIdx.x >> 5;
        int i0 = 20 * s;
        const float* ln = tin[r];
        float sum = 0.f;
        int jlo = i0 - 16; if (jlo < 0) jlo = 0;
        int jhi = i0 + 15; if (jhi > D - 1) jhi = D - 1;
        for (int j = jlo; j <= jhi; ++j) sum += ln[j];
        #pragma unroll 4
        for (int k = 0; k < 20; ++k) {
            int i = i0 + k;
            filt[i][r] = sum;
            int add = i + 16, rem = i - 16;
            if (add <= D - 1) sum += ln[add];
            if (rem >= 0)     sum -= ln[rem];
        }
    }
    __syncthreads();

    int r = threadIdx.x & 31;
    int L = L0 + r;
    int y = L / D, z = L - (L / D) * D;
    bool byz = (y >= HALF && y < D - HALF && z >= HALF && z < D - HALF);
    int wy = min(y + 15, D - 1) - max(y - 16, 0) + 1;
    int wz = min(z + 15, D - 1) - max(z - 16, 0) + 1;
    for (int c = (threadIdx.x >> 5); c < D; c += 8) {   // c == x
        int p = c * DD + L;
        unsigned pk = cwp[p];
        unsigned cw0 = pk & 0xFFFFu;
        unsigned cw1 = pk >> 16;
        int wx = min(c + 15, D - 1) - max(c - 16, 0) + 1;
        unsigned cw2 = (unsigned)(wx * wy * wz) - cw0 - cw1;
        float v0 = (cw0 > 100u) ? 1.f : 0.f;
        float v1 = (cw1 > 100u) ? 1.f : 0.f;
        float v2 = (cw2 > 100u) ? 1.f : 0.f;
        float border = (byz && c >= HALF && c < D - HALF) ? 1.f : 0.f;
        float cd = (border * v1 + v0 + v2 >= 2.f) ? 1.f : 0.f;
        cand[p] = cd;
        float mean = (cw1 > 0u) ? filt[c][r] / fmaxf((float)cw1, 1.f) : 0.f;
        int idx = (int)rintf(cd * mean);    // round half-to-even == jnp.round
        idx = min(max(idx, 0), NBINS - 1);
        idxbuf[p] = (unsigned short)idx;
        if (idx != 0) atomicAdd(&lh[idx], 1);   // hist[0] never consumed
    }
    __syncthreads();
    int* po = partial + blockIdx.x * NBINS;
    for (int i = threadIdx.x; i < NBINS; i += 256) po[i] = lh[i];
}

// ---------------------------------------------------------------------------
// Persistent flag-pipelined CCL: 16 synchronous 6-neighbor min sweeps +
// component count in ONE plain launch (no grid.sync — R8 measured it at
// ~280 us per sync). 20 x-slabs x 50 blocks; sweep g of slab k proceeds when
// flags fl[g-1][k-1,k,k+1] hit 50 (same condition protects the ping-pong
// overwrite -> WAR-safe). Acquire __threadfence() after wait (L1 served
// stale lines in R8 when this was missing), release fence before publish.
// 1000 blocks @ launch_bounds(256,4) -> all co-resident, deadlock-free;
// bounded spins are hang insurance only.
// ---------------------------------------------------------------------------
__device__ __forceinline__ int min6(int c, int a, int b, int d, int e, int f, int g) {
    if (c == BIGV) return BIGV;
    return min(min(min(c, a), min(b, d)), min(min(e, f), g));
}

__device__ __forceinline__ void wave_count(int l, int lane, int* __restrict__ cnt) {
    unsigned long long remaining = __ballot(l != BIGV);
    while (remaining) {
        int leader = __ffsll((unsigned long long)remaining) - 1;
        int ll = __shfl(l, leader, 64);
        unsigned long long mm = __ballot(l == ll);
        if (lane == leader) atomicAdd(&cnt[ll], (int)__popcll(mm & remaining));
        remaining &= ~mm;
    }
}

__device__ __forceinline__ void wait_flag(int* f, int target) {
    for (int i = 0; i < 50000000; ++i) {   // bounded: hang insurance only
        int v = __hip_atomic_load(f, __ATOMIC_RELAXED, __HIP_MEMORY_SCOPE_AGENT);
        if (v >= target) return;
        __builtin_amdgcn_s_sleep(2);
    }
}

__global__ __launch_bounds__(256, 4) void ccl_persist_kernel(
    int* __restrict__ bufA, int* __restrict__ bufB,
    int* __restrict__ cnt, int* flags)
{
    int b = blockIdx.x;
    int k = b % NSLAB;                       // slab id (b%20: ~2 XCDs/slab)
    int t = (b / NSLAB) * 256 + threadIdx.x; // 0..12799 within slab
    int p = k * (8 * DD) + t * CPT;          // global cell base (slab contig)
    int q = p >> 2;                          // int4 index
    int lane = threadIdx.x & 63;
    int z0 = p % D;                          // multiple of 16
    int r = p / D;
    int y = r % D;
    int x = r / D;
    const int4 BIG4 = make_int4(BIGV, BIGV, BIGV, BIGV);

    int4 c[4];
    {
        const int4* a4 = (const int4*)bufA;
        #pragma unroll
        for (int j = 0; j < 4; ++j) c[j] = a4[q + j];
    }

    int* src = bufA;
    int* dst = bufB;
    for (int g = 1; g <= NSWEEP; ++g) {
        if (g > 1) {
            if (threadIdx.x == 0) {
                wait_flag(&flags[(g - 1) * 32 + k], BLKSLAB);
                if (k > 0)         wait_flag(&flags[(g - 1) * 32 + k - 1], BLKSLAB);
                if (k < NSLAB - 1) wait_flag(&flags[(g - 1) * 32 + k + 1], BLKSLAB);
            }
            __syncthreads();
            __threadfence();                 // ACQUIRE: invalidate L1 before reads
        }

        int lm = __shfl_up(c[3].w, 1);       // lab[p-1]
        int rm = __shfl_down(c[0].x, 1);     // lab[p+CPT]
        if (z0 == 0)           lm = BIGV;
        else if (lane == 0)    lm = src[p - 1];
        if (z0 == D - CPT)     rm = BIGV;
        else if (lane == 63)   rm = src[p + CPT];

        const int4* s4 = (const int4*)src;
        int4 yl[4], yh[4], xl[4], xh[4];
        #pragma unroll
        for (int j = 0; j < 4; ++j) {
            yl[j] = (y > 0)     ? s4[q - D/4 + j]  : BIG4;
            yh[j] = (y < D - 1) ? s4[q + D/4 + j]  : BIG4;
            xl[j] = (x > 0)     ? s4[q - DD/4 + j] : BIG4;
            xh[j] = (x < D - 1) ? s4[q + DD/4 + j] : BIG4;
        }

        int4 o[4];
        #pragma unroll
        for (int j = 0; j < 4; ++j) {
            int zlo = (j == 0) ? lm : c[j-1].w;
            int zhi = (j == 3) ? rm : c[j+1].x;
            o[j].x = min6(c[j].x, zlo,    c[j].y, yl[j].x, yh[j].x, xl[j].x, xh[j].x);
            o[j].y = min6(c[j].y, c[j].x, c[j].z, yl[j].y, yh[j].y, xl[j].y, xh[j].y);
            o[j].z = min6(c[j].z, c[j].y, c[j].w, yl[j].z, yh[j].z, xl[j].z, xh[j].z);
            o[j].w = min6(c[j].w, c[j].z, zhi,    yl[j].w, yh[j].w, xl[j].w, xh[j].w);
        }

        int4* d4 = (int4*)dst;
        #pragma unroll
        for (int j = 0; j < 4; ++j) { d4[q + j] = o[j]; c[j] = o[j]; }

        __threadfence();                     // RELEASE: writes visible device-wide
        __syncthreads();
        if (threadIdx.x == 0)
            atomicAdd(&flags[g * 32 + k], 1);

        int* tmp = src; src = dst; dst = tmp;
    }

    // final labels (gen 16, even -> in bufA) already in registers: count
    #pragma unroll
    for (int j = 0; j < 4; ++j) {
        wave_count(c[j].x, lane, cnt);
        wave_count(c[j].y, lane, cnt);
        wave_count(c[j].z, lane, cnt);
        wave_count(c[j].w, lane, cnt);
    }
}

// ---------------------------------------------------------------------------
// hist[bin] = sum over RGRID block partials (coalesced, L2-resident)
// ---------------------------------------------------------------------------
__global__ __launch_bounds__(256) void hist_reduce_kernel(
    const int* __restrict__ partial, int* __restrict__ hist)
{
    int bin = blockIdx.x * 256 + threadIdx.x;   // 16 x 256 = 4096
    int s = 0;
    #pragma unroll 4
    for (int b = 0; b < RGRID; ++b) s += partial[b * NBINS + bin];
    hist[bin] = s;
}

// ---------------------------------------------------------------------------
// histogram post-processing: rec -> ph_full (normalized), S = sum hist*ph.
// Guards (sumrec>0, S>0) degrade an all-zero histogram to 0 instead of NaN.
// ---------------------------------------------------------------------------
__global__ __launch_bounds__(256) void hist_post_kernel(
    const int* __restrict__ hist, float* __restrict__ ph_full,
    float* __restrict__ Sout)
{
    __shared__ float red[256];
    int t = threadIdx.x;

    float loc = 0.f;
    for (int b = t; b < NBINS; b += 256)
        if (b >= 1) loc += (float)hist[b];
    red[t] = loc; __syncthreads();
    for (int o = 128; o > 0; o >>= 1) { if (t < o) red[t] += red[t + o]; __syncthreads(); }
    float numb = red[0]; __syncthreads();

    loc = 0.f;
    for (int b = t; b < NBINS; b += 256) {
        float r = 0.f;
        if (b >= 1) {
            int h = hist[b];
            if (h > 0) r = numb / (float)h;
        }
        ph_full[b] = r;
        loc += r;
    }
    red[t] = loc; __syncthreads();
    for (int o = 128; o > 0; o >>= 1) { if (t < o) red[t] += red[t + o]; __syncthreads(); }
    float sumrec = red[0]; __syncthreads();
    float inv_sumrec = (sumrec > 0.f) ? 1.f / sumrec : 0.f;

    loc = 0.f;
    for (int b = t; b < NBINS; b += 256) {
        float ph = (b >= 1) ? ph_full[b] * inv_sumrec : 0.f;
        ph_full[b] = ph;
        loc += ph * (float)hist[b];
    }
    red[t] = loc; __syncthreads();
    for (int o = 128; o > 0; o >>= 1) { if (t < o) red[t] += red[t + o]; __syncthreads(); }
    if (t == 0) Sout[0] = (red[0] > 0.f) ? red[0] : 1.f;
}

__global__ __launch_bounds__(256) void proba_kernel(
    const unsigned short* __restrict__ idxbuf,
    const float* __restrict__ ph_full, const float* __restrict__ Sv,
    float* __restrict__ outp)
{
    int p = blockIdx.x * blockDim.x + threadIdx.x;   // exact grid
    outp[p] = ph_full[idxbuf[p]] / Sv[0];
}

// ---------------------------------------------------------------------------
extern "C" void kernel_launch(void* const* d_in, const int* in_sizes, int n_in,
                              void* d_out, int out_size, void* d_ws, size_t ws_size,
                              hipStream_t stream)
{
    const float* data = (const float*)d_in[0];
    float* out   = (float*)d_out;
    float* cand  = out;
    float* proba = out + NVOX;

    char* ws = (char*)d_ws;
    const size_t NB = (size_t)NVOX * sizeof(float);
    float* W1 = (float*)(ws);
    float* W2 = (float*)(ws + NB);
    float* W3 = (float*)(ws + 2 * NB);
    int*   cnt  = (int*)(ws + 3 * NB);                 // NVOX+1 ints
    float* ph   = (float*)(ws + 4 * NB + 16);
    int*   hist = (int*)  (ws + 4 * NB + 16 + NBINS * 4);
    float* Sv   = (float*)(ws + 4 * NB + 16 + 2 * NBINS * 4);
    int*   flags = (int*) (ws + 4 * NB + 16 + 2 * NBINS * 4 + 64);  // (NSWEEP+1)*32
    unsigned short* idxbuf = (unsigned short*)cnt;     // cnt dead after cs pass 1
    int* partial = (int*)W3;                           // W3 dead after cs pass 2

    dim3 eb(256), eg(NVOX / 256);          // 16000 blocks (proba)
    dim3 rb(256), rg(RGRID);               // 800 blocks (rotate passes)

    hipMemsetAsync(cnt, 0, (NVOX + 1) * sizeof(int), stream);
    hipMemsetAsync(flags, 0, (NSWEEP + 1) * 32 * sizeof(int), stream);

    // cw packed box sums via rotate pipeline (pass 1 fuses pack + lab init)
    box_rot_int_kernel<0><<<rg, rb, 0, stream>>>(data, (unsigned*)W1, (int*)W2);
    box_rot_int_kernel<1><<<rg, rb, 0, stream>>>(W1, (unsigned*)W3, nullptr);
    box_rot_int_kernel<1><<<rg, rb, 0, stream>>>(W3, (unsigned*)W1, nullptr);
    unsigned* cwp = (unsigned*)W1;         // original layout

    // CCL: 16 synchronous sweeps + count, one persistent flag-pipelined
    // launch. Ping-pong W2<->W3; even sweep count -> final labels in W2.
    ccl_persist_kernel<<<dim3(PGRID), dim3(256), 0, stream>>>(
        (int*)W2, (int*)W3, cnt, flags);
    int* lab = (int*)W2;

    // cs float box sums (pass 1 fuses lsize*valid gather; pass 3 fuses
    // finalize: cand + idx + histogram — cs never materialized)
    box_rot_f32_g_kernel<<<rg, rb, 0, stream>>>(lab, cnt, cwp, W3);
    box_rot_f32_kernel<<<rg, rb, 0, stream>>>(W3, W2);
    box_rot_fin_kernel<<<rg, rb, 0, stream>>>(W2, cwp, cand, idxbuf, partial);

    hist_reduce_kernel<<<dim3(16), dim3(256), 0, stream>>>(partial, hist);
    hist_post_kernel<<<1, 256, 0, stream>>>(hist, ph, Sv);
    proba_kernel<<<eg, eb, 0, stream>>>(idxbuf, ph, Sv, proba);
}

// Round 10
// 843.781 us; speedup vs baseline: 5.8117x; 5.8117x over previous
//
#include <hip/hip_runtime.h>
#include <cmath>

#define D 160
#define DD (D*D)          // 25600
#define NVOX (D*D*D)
#define BIGV (NVOX + 2)
#define NBINS 4096
#define HALF 16
#define RGRID 800         // rotate-pass blocks = DD/32, also hist partial count
#define CPT 16            // cells per thread in CCL sweeps
#define SGRID (NVOX / CPT / 256)   // 1000 sweep blocks
#define NSWEEP 16

// ---------------------------------------------------------------------------
// Rotate-pipeline box filter (window 32, 'same'), INT packed path.
// Buffer layout (a,b,c) c-contiguous; filter along c; write out[c*DD+a*D+b]
// -> layout (c,a,b). Three passes return to identity with each axis filtered.
// MODE 0 fuses class-pack from raw data + CCL lab init (original layout).
// cw0 low 16 bits, cw1 high 16 (max 32768, no carry). Int sums order-free.
// ---------------------------------------------------------------------------
template<int MODE>
__global__ __launch_bounds__(256) void box_rot_int_kernel(
    const void* __restrict__ vin, unsigned* __restrict__ out,
    int* __restrict__ lab)
{
    __shared__ unsigned tin[32][161];
    __shared__ unsigned filt[160][33];
    int L0 = blockIdx.x * 32;
    size_t base = (size_t)L0 * D;

    if (MODE == 0) {
        const float4* s4 = (const float4*)((const float*)vin + base);
        int4* lab4 = (int4*)(lab + base);
        for (int i = threadIdx.x; i < 32 * (D / 4); i += 256) {
            float4 v = s4[i];
            int e = i * 4, r = e / D, c = e - r * D;
            int p = (int)base + e;
            int4 lb; float rr;
            rr = rintf(v.x); tin[r][c]   = (rr==0.f) | ((rr==1.f)?0x10000u:0u); lb.x = (rr==1.f)?(p+1):BIGV;
            rr = rintf(v.y); tin[r][c+1] = (rr==0.f) | ((rr==1.f)?0x10000u:0u); lb.y = (rr==1.f)?(p+2):BIGV;
            rr = rintf(v.z); tin[r][c+2] = (rr==0.f) | ((rr==1.f)?0x10000u:0u); lb.z = (rr==1.f)?(p+3):BIGV;
            rr = rintf(v.w); tin[r][c+3] = (rr==0.f) | ((rr==1.f)?0x10000u:0u); lb.w = (rr==1.f)?(p+4):BIGV;
            lab4[i] = lb;
        }
    } else {
        const uint4* s4 = (const uint4*)((const unsigned*)vin + base);
        for (int i = threadIdx.x; i < 32 * (D / 4); i += 256) {
            uint4 v = s4[i];
            int e = i * 4, r = e / D, c = e - r * D;
            tin[r][c] = v.x; tin[r][c+1] = v.y; tin[r][c+2] = v.z; tin[r][c+3] = v.w;
        }
    }
    __syncthreads();

    {
        int r = threadIdx.x & 31, s = threadIdx.x >> 5;
        int i0 = 20 * s;
        const unsigned* ln = tin[r];
        unsigned sum = 0u;
        int jlo = i0 - 16; if (jlo < 0) jlo = 0;
        int jhi = i0 + 15; if (jhi > D - 1) jhi = D - 1;
        for (int j = jlo; j <= jhi; ++j) sum += ln[j];
        #pragma unroll 4
        for (int k = 0; k < 20; ++k) {
            int i = i0 + k;
            filt[i][r] = sum;
            int add = i + 16, rem = i - 16;
            if (add <= D - 1) sum += ln[add];
            if (rem >= 0)     sum -= ln[rem];
        }
    }
    __syncthreads();

    int r = threadIdx.x & 31;
    for (int c = (threadIdx.x >> 5); c < D; c += 8)
        out[(size_t)c * DD + L0 + r] = filt[c][r];
}

// ---------------------------------------------------------------------------
// Rotate box filter, FLOAT path, pass 1: fuses the lsize*valid gather.
// fp order differs from reference cumsum: perturbs only proba (~1e-7 vs
// 2e-2 threshold); candidates are integer-exact.
// ---------------------------------------------------------------------------
__global__ __launch_bounds__(256) void box_rot_f32_g_kernel(
    const int* __restrict__ lab, const int* __restrict__ cnt,
    const unsigned* __restrict__ cwp, float* __restrict__ out)
{
    __shared__ float tin[32][161];
    __shared__ float filt[160][33];
    int L0 = blockIdx.x * 32;
    size_t base = (size_t)L0 * D;

    const int4*  lab4 = (const int4*)(lab + base);
    const uint4* cw4  = (const uint4*)(cwp + base);
    for (int i = threadIdx.x; i < 32 * (D / 4); i += 256) {
        int4 l = lab4[i];
        uint4 cw = cw4[i];
        int e = i * 4, r = e / D, c = e - r * D;
        tin[r][c]   = (l.x != BIGV && (cw.x >> 16) > 100u) ? (float)cnt[l.x] : 0.f;
        tin[r][c+1] = (l.y != BIGV && (cw.y >> 16) > 100u) ? (float)cnt[l.y] : 0.f;
        tin[r][c+2] = (l.z != BIGV && (cw.z >> 16) > 100u) ? (float)cnt[l.z] : 0.f;
        tin[r][c+3] = (l.w != BIGV && (cw.w >> 16) > 100u) ? (float)cnt[l.w] : 0.f;
    }
    __syncthreads();

    {
        int r = threadIdx.x & 31, s = threadIdx.x >> 5;
        int i0 = 20 * s;
        const float* ln = tin[r];
        float sum = 0.f;
        int jlo = i0 - 16; if (jlo < 0) jlo = 0;
        int jhi = i0 + 15; if (jhi > D - 1) jhi = D - 1;
        for (int j = jlo; j <= jhi; ++j) sum += ln[j];
        #pragma unroll 4
        for (int k = 0; k < 20; ++k) {
            int i = i0 + k;
            filt[i][r] = sum;
            int add = i + 16, rem = i - 16;
            if (add <= D - 1) sum += ln[add];
            if (rem >= 0)     sum -= ln[rem];
        }
    }
    __syncthreads();

    int r = threadIdx.x & 31;
    for (int c = (threadIdx.x >> 5); c < D; c += 8)
        out[(size_t)c * DD + L0 + r] = filt[c][r];
}

// plain float middle pass
__global__ __launch_bounds__(256) void box_rot_f32_kernel(
    const float* __restrict__ fin, float* __restrict__ out)
{
    __shared__ float tin[32][161];
    __shared__ float filt[160][33];
    int L0 = blockIdx.x * 32;
    size_t base = (size_t)L0 * D;

    const float4* s4 = (const float4*)(fin + base);
    for (int i = threadIdx.x; i < 32 * (D / 4); i += 256) {
        float4 v = s4[i];
        int e = i * 4, r = e / D, c = e - r * D;
        tin[r][c] = v.x; tin[r][c+1] = v.y; tin[r][c+2] = v.z; tin[r][c+3] = v.w;
    }
    __syncthreads();

    {
        int r = threadIdx.x & 31, s = threadIdx.x >> 5;
        int i0 = 20 * s;
        const float* ln = tin[r];
        float sum = 0.f;
        int jlo = i0 - 16; if (jlo < 0) jlo = 0;
        int jhi = i0 + 15; if (jhi > D - 1) jhi = D - 1;
        for (int j = jlo; j <= jhi; ++j) sum += ln[j];
        #pragma unroll 4
        for (int k = 0; k < 20; ++k) {
            int i = i0 + k;
            filt[i][r] = sum;
            int add = i + 16, rem = i - 16;
            if (add <= D - 1) sum += ln[add];
            if (rem >= 0)     sum -= ln[rem];
        }
    }
    __syncthreads();

    int r = threadIdx.x & 31;
    for (int c = (threadIdx.x >> 5); c < D; c += 8)
        out[(size_t)c * DD + L0 + r] = filt[c][r];
}

// ---------------------------------------------------------------------------
// cs pass 3 fused with finalize: filter along x; compute candidates / bin
// idx / LDS histogram directly (cs never materialized).
// Input layout (y,z,x): line L = y*D+z, elems along x. Output p = x*DD+L.
// ---------------------------------------------------------------------------
__global__ __launch_bounds__(256) void box_rot_fin_kernel(
    const float* __restrict__ fin, const unsigned* __restrict__ cwp,
    float* __restrict__ cand, unsigned short* __restrict__ idxbuf,
    int* __restrict__ partial)
{
    __shared__ float tin[32][161];
    __shared__ float filt[160][33];
    __shared__ int lh[NBINS];
    for (int i = threadIdx.x; i < NBINS; i += 256) lh[i] = 0;

    int L0 = blockIdx.x * 32;
    size_t base = (size_t)L0 * D;
    const float4* s4 = (const float4*)(fin + base);
    for (int i = threadIdx.x; i < 32 * (D / 4); i += 256) {
        float4 v = s4[i];
        int e = i * 4, r = e / D, c = e - r * D;
        tin[r][c] = v.x; tin[r][c+1] = v.y; tin[r][c+2] = v.z; tin[r][c+3] = v.w;
    }
    __syncthreads();

    {
        int r = threadIdx.x & 31, s = threadIdx.x >> 5;
        int i0 = 20 * s;
        const float* ln = tin[r];
        float sum = 0.f;
        int jlo = i0 - 16; if (jlo < 0) jlo = 0;
        int jhi = i0 + 15; if (jhi > D - 1) jhi = D - 1;
        for (int j = jlo; j <= jhi; ++j) sum += ln[j];
        #pragma unroll 4
        for (int k = 0; k < 20; ++k) {
            int i = i0 + k;
            filt[i][r] = sum;
            int add = i + 16, rem = i - 16;
            if (add <= D - 1) sum += ln[add];
            if (rem >= 0)     sum -= ln[rem];
        }
    }
    __syncthreads();

    int r = threadIdx.x & 31;
    int L = L0 + r;
    int y = L / D, z = L - (L / D) * D;
    bool byz = (y >= HALF && y < D - HALF && z >= HALF && z < D - HALF);
    int wy = min(y + 15, D - 1) - max(y - 16, 0) + 1;
    int wz = min(z + 15, D - 1) - max(z - 16, 0) + 1;
    for (int c = (threadIdx.x >> 5); c < D; c += 8) {   // c == x
        int p = c * DD + L;
        unsigned pk = cwp[p];
        unsigned cw0 = pk & 0xFFFFu;
        unsigned cw1 = pk >> 16;
        int wx = min(c + 15, D - 1) - max(c - 16, 0) + 1;
        unsigned cw2 = (unsigned)(wx * wy * wz) - cw0 - cw1;
        float v0 = (cw0 > 100u) ? 1.f : 0.f;
        float v1 = (cw1 > 100u) ? 1.f : 0.f;
        float v2 = (cw2 > 100u) ? 1.f : 0.f;
        float border = (byz && c >= HALF && c < D - HALF) ? 1.f : 0.f;
        float cd = (border * v1 + v0 + v2 >= 2.f) ? 1.f : 0.f;
        cand[p] = cd;
        float mean = (cw1 > 0u) ? filt[c][r] / fmaxf((float)cw1, 1.f) : 0.f;
        int idx = (int)rintf(cd * mean);    // round half-to-even == jnp.round
        idx = min(max(idx, 0), NBINS - 1);
        idxbuf[p] = (unsigned short)idx;
        if (idx != 0) atomicAdd(&lh[idx], 1);   // hist[0] never consumed
    }
    __syncthreads();
    int* po = partial + blockIdx.x * NBINS;
    for (int i = threadIdx.x; i < NBINS; i += 256) po[i] = lh[i];
}

// ---------------------------------------------------------------------------
// Flat CCL sweep, one launch per sweep (multi-launch is the fastest scheme
// measured: grid.sync (R8) and flag-spin pipelines (R9) both cost ~270 us
// per cross-block generation — 10x worse than runtime-managed launches).
// CPT=16 cells per thread (4 int4 quads), z-edges via wave shuffle.
// XCD-aware swizzle: sb = (b&7)*125 + (b>>3) gives each XCD a contiguous
// 20-plane x-slab (2 MB, L2-resident) so x+-1 plane reads hit the local L2
// instead of re-fetching from HBM (R6 FETCH was 1.76x volume without this).
// ---------------------------------------------------------------------------
__device__ __forceinline__ int min6(int c, int a, int b, int d, int e, int f, int g) {
    if (c == BIGV) return BIGV;
    return min(min(min(c, a), min(b, d)), min(min(e, f), g));
}

__device__ __forceinline__ void wave_count(int l, int lane, int* __restrict__ cnt) {
    unsigned long long remaining = __ballot(l != BIGV);
    while (remaining) {
        int leader = __ffsll((unsigned long long)remaining) - 1;
        int ll = __shfl(l, leader, 64);
        unsigned long long mm = __ballot(l == ll);
        if (lane == leader) atomicAdd(&cnt[ll], (int)__popcll(mm & remaining));
        remaining &= ~mm;
    }
}

template<int COUNT>
__global__ __launch_bounds__(256) void ccl_sweep16_kernel(
    const int* __restrict__ lab, int* __restrict__ outp, int* __restrict__ cnt)
{
    int b = blockIdx.x;                          // 0..999
    int sb = (b & 7) * (SGRID / 8) + (b >> 3);   // XCD-contiguous x-slab
    int t = sb * 256 + threadIdx.x;
    int p = t * CPT;
    int q = p >> 2;                              // int4 index
    int lane = threadIdx.x & 63;
    int z0 = p % D;                              // multiple of 16
    int r = p / D;
    int y = r % D;
    int x = r / D;
    const int4 BIG4 = make_int4(BIGV, BIGV, BIGV, BIGV);

    const int4* s4 = (const int4*)lab;
    int4 c[4];
    #pragma unroll
    for (int j = 0; j < 4; ++j) c[j] = s4[q + j];

    int lm = __shfl_up(c[3].w, 1);       // lab[p-1]
    int rm = __shfl_down(c[0].x, 1);     // lab[p+CPT]
    if (z0 == 0)           lm = BIGV;
    else if (lane == 0)    lm = lab[p - 1];
    if (z0 == D - CPT)     rm = BIGV;
    else if (lane == 63)   rm = lab[p + CPT];

    int4 yl[4], yh[4], xl[4], xh[4];
    #pragma unroll
    for (int j = 0; j < 4; ++j) {
        yl[j] = (y > 0)     ? s4[q - D/4 + j]  : BIG4;
        yh[j] = (y < D - 1) ? s4[q + D/4 + j]  : BIG4;
        xl[j] = (x > 0)     ? s4[q - DD/4 + j] : BIG4;
        xh[j] = (x < D - 1) ? s4[q + DD/4 + j] : BIG4;
    }

    int4 o[4];
    #pragma unroll
    for (int j = 0; j < 4; ++j) {
        int zlo = (j == 0) ? lm : c[j-1].w;
        int zhi = (j == 3) ? rm : c[j+1].x;
        o[j].x = min6(c[j].x, zlo,    c[j].y, yl[j].x, yh[j].x, xl[j].x, xh[j].x);
        o[j].y = min6(c[j].y, c[j].x, c[j].z, yl[j].y, yh[j].y, xl[j].y, xh[j].y);
        o[j].z = min6(c[j].z, c[j].y, c[j].w, yl[j].z, yh[j].z, xl[j].z, xh[j].z);
        o[j].w = min6(c[j].w, c[j].z, zhi,    yl[j].w, yh[j].w, xl[j].w, xh[j].w);
    }

    int4* d4 = (int4*)outp;
    #pragma unroll
    for (int j = 0; j < 4; ++j) d4[q + j] = o[j];

    if (COUNT) {   // final sweep: component-size count from registers
        #pragma unroll
        for (int j = 0; j < 4; ++j) {
            wave_count(o[j].x, lane, cnt);
            wave_count(o[j].y, lane, cnt);
            wave_count(o[j].z, lane, cnt);
            wave_count(o[j].w, lane, cnt);
        }
    }
}

// ---------------------------------------------------------------------------
// hist[bin] = sum over RGRID block partials (coalesced, L2-resident)
// ---------------------------------------------------------------------------
__global__ __launch_bounds__(256) void hist_reduce_kernel(
    const int* __restrict__ partial, int* __restrict__ hist)
{
    int bin = blockIdx.x * 256 + threadIdx.x;   // 16 x 256 = 4096
    int s = 0;
    #pragma unroll 4
    for (int b = 0; b < RGRID; ++b) s += partial[b * NBINS + bin];
    hist[bin] = s;
}

// ---------------------------------------------------------------------------
// histogram post-processing: rec -> ph_full (normalized), S = sum hist*ph.
// Guards (sumrec>0, S>0) degrade an all-zero histogram to 0 instead of NaN.
// ---------------------------------------------------------------------------
__global__ __launch_bounds__(256) void hist_post_kernel(
    const int* __restrict__ hist, float* __restrict__ ph_full,
    float* __restrict__ Sout)
{
    __shared__ float red[256];
    int t = threadIdx.x;

    float loc = 0.f;
    for (int b = t; b < NBINS; b += 256)
        if (b >= 1) loc += (float)hist[b];
    red[t] = loc; __syncthreads();
    for (int o = 128; o > 0; o >>= 1) { if (t < o) red[t] += red[t + o]; __syncthreads(); }
    float numb = red[0]; __syncthreads();

    loc = 0.f;
    for (int b = t; b < NBINS; b += 256) {
        float r = 0.f;
        if (b >= 1) {
            int h = hist[b];
            if (h > 0) r = numb / (float)h;
        }
        ph_full[b] = r;
        loc += r;
    }
    red[t] = loc; __syncthreads();
    for (int o = 128; o > 0; o >>= 1) { if (t < o) red[t] += red[t + o]; __syncthreads(); }
    float sumrec = red[0]; __syncthreads();
    float inv_sumrec = (sumrec > 0.f) ? 1.f / sumrec : 0.f;

    loc = 0.f;
    for (int b = t; b < NBINS; b += 256) {
        float ph = (b >= 1) ? ph_full[b] * inv_sumrec : 0.f;
        ph_full[b] = ph;
        loc += ph * (float)hist[b];
    }
    red[t] = loc; __syncthreads();
    for (int o = 128; o > 0; o >>= 1) { if (t < o) red[t] += red[t + o]; __syncthreads(); }
    if (t == 0) Sout[0] = (red[0] > 0.f) ? red[0] : 1.f;
}

__global__ __launch_bounds__(256) void proba_kernel(
    const unsigned short* __restrict__ idxbuf,
    const float* __restrict__ ph_full, const float* __restrict__ Sv,
    float* __restrict__ outp)
{
    int p = blockIdx.x * blockDim.x + threadIdx.x;   // exact grid
    outp[p] = ph_full[idxbuf[p]] / Sv[0];
}

// ---------------------------------------------------------------------------
extern "C" void kernel_launch(void* const* d_in, const int* in_sizes, int n_in,
                              void* d_out, int out_size, void* d_ws, size_t ws_size,
                              hipStream_t stream)
{
    const float* data = (const float*)d_in[0];
    float* out   = (float*)d_out;
    float* cand  = out;
    float* proba = out + NVOX;

    char* ws = (char*)d_ws;
    const size_t NB = (size_t)NVOX * sizeof(float);
    float* W1 = (float*)(ws);
    float* W2 = (float*)(ws + NB);
    float* W3 = (float*)(ws + 2 * NB);
    int*   cnt  = (int*)(ws + 3 * NB);                 // NVOX+1 ints
    float* ph   = (float*)(ws + 4 * NB + 16);
    int*   hist = (int*)  (ws + 4 * NB + 16 + NBINS * 4);
    float* Sv   = (float*)(ws + 4 * NB + 16 + 2 * NBINS * 4);
    unsigned short* idxbuf = (unsigned short*)cnt;     // cnt dead after cs pass 1
    int* partial = (int*)W3;                           // W3 dead after cs pass 2

    dim3 eb(256), eg(NVOX / 256);          // 16000 blocks (proba)
    dim3 rb(256), rg(RGRID);               // 800 blocks (rotate passes)
    dim3 sbk(256), sg(SGRID);              // 1000 blocks (sweeps)

    hipMemsetAsync(cnt, 0, (NVOX + 1) * sizeof(int), stream);

    // cw packed box sums via rotate pipeline (pass 1 fuses pack + lab init)
    box_rot_int_kernel<0><<<rg, rb, 0, stream>>>(data, (unsigned*)W1, (int*)W2);
    box_rot_int_kernel<1><<<rg, rb, 0, stream>>>(W1, (unsigned*)W3, nullptr);
    box_rot_int_kernel<1><<<rg, rb, 0, stream>>>(W3, (unsigned*)W1, nullptr);
    unsigned* cwp = (unsigned*)W1;         // original layout

    // CCL: 16 flat synchronous sweeps, ping-pong W2 <-> W3;
    // sweep 16 fuses the component-size count (labels already in registers)
    for (int s = 0; s < NSWEEP - 1; ++s) {
        const int* src = (s & 1) ? (int*)W3 : (int*)W2;
        int*       dst = (s & 1) ? (int*)W2 : (int*)W3;
        ccl_sweep16_kernel<0><<<sg, sbk, 0, stream>>>(src, dst, nullptr);
    }
    ccl_sweep16_kernel<1><<<sg, sbk, 0, stream>>>((int*)W3, (int*)W2, cnt);
    int* lab = (int*)W2;

    // cs float box sums (pass 1 fuses lsize*valid gather; pass 3 fuses
    // finalize: cand + idx + histogram — cs never materialized)
    box_rot_f32_g_kernel<<<rg, rb, 0, stream>>>(lab, cnt, cwp, W3);
    box_rot_f32_kernel<<<rg, rb, 0, stream>>>(W3, W2);
    box_rot_fin_kernel<<<rg, rb, 0, stream>>>(W2, cwp, cand, idxbuf, partial);

    hist_reduce_kernel<<<dim3(16), dim3(256), 0, stream>>>(partial, hist);
    hist_post_kernel<<<1, 256, 0, stream>>>(hist, ph, Sv);
    proba_kernel<<<eg, eb, 0, stream>>>(idxbuf, ph, Sv, proba);
}

// Round 11
// 426.536 us; speedup vs baseline: 11.4968x; 1.9782x over previous
//
#include <hip/hip_runtime.h>
#include <cmath>

#define D 160
#define DD (D*D)          // 25600
#define NVOX (D*D*D)
#define BIGV (NVOX + 2)
#define NBINS 4096
#define HALF 16
#define RGRID 800         // rotate-pass blocks = DD/32, also hist partial count
#define SGRID (NVOX / 8 / 256)   // 2000 sweep blocks (8 cells/thread)
#define NSWEEP 16

// ---------------------------------------------------------------------------
// Rotate-pipeline box filter (window 32, 'same'), INT packed path.
// Buffer layout (a,b,c) c-contiguous; filter along c; write out[c*DD+a*D+b]
// -> layout (c,a,b). Three passes return to identity with each axis filtered.
// MODE 0 fuses class-pack from raw data + CCL lab init (original layout).
// cw0 low 16 bits, cw1 high 16 (max 32768, no carry). Int sums order-free.
// ---------------------------------------------------------------------------
template<int MODE>
__global__ __launch_bounds__(256) void box_rot_int_kernel(
    const void* __restrict__ vin, unsigned* __restrict__ out,
    int* __restrict__ lab)
{
    __shared__ unsigned tin[32][161];
    __shared__ unsigned filt[160][33];
    int L0 = blockIdx.x * 32;
    size_t base = (size_t)L0 * D;

    if (MODE == 0) {
        const float4* s4 = (const float4*)((const float*)vin + base);
        int4* lab4 = (int4*)(lab + base);
        for (int i = threadIdx.x; i < 32 * (D / 4); i += 256) {
            float4 v = s4[i];
            int e = i * 4, r = e / D, c = e - r * D;
            int p = (int)base + e;
            int4 lb; float rr;
            rr = rintf(v.x); tin[r][c]   = (rr==0.f) | ((rr==1.f)?0x10000u:0u); lb.x = (rr==1.f)?(p+1):BIGV;
            rr = rintf(v.y); tin[r][c+1] = (rr==0.f) | ((rr==1.f)?0x10000u:0u); lb.y = (rr==1.f)?(p+2):BIGV;
            rr = rintf(v.z); tin[r][c+2] = (rr==0.f) | ((rr==1.f)?0x10000u:0u); lb.z = (rr==1.f)?(p+3):BIGV;
            rr = rintf(v.w); tin[r][c+3] = (rr==0.f) | ((rr==1.f)?0x10000u:0u); lb.w = (rr==1.f)?(p+4):BIGV;
            lab4[i] = lb;
        }
    } else {
        const uint4* s4 = (const uint4*)((const unsigned*)vin + base);
        for (int i = threadIdx.x; i < 32 * (D / 4); i += 256) {
            uint4 v = s4[i];
            int e = i * 4, r = e / D, c = e - r * D;
            tin[r][c] = v.x; tin[r][c+1] = v.y; tin[r][c+2] = v.z; tin[r][c+3] = v.w;
        }
    }
    __syncthreads();

    {
        int r = threadIdx.x & 31, s = threadIdx.x >> 5;
        int i0 = 20 * s;
        const unsigned* ln = tin[r];
        unsigned sum = 0u;
        int jlo = i0 - 16; if (jlo < 0) jlo = 0;
        int jhi = i0 + 15; if (jhi > D - 1) jhi = D - 1;
        for (int j = jlo; j <= jhi; ++j) sum += ln[j];
        #pragma unroll 4
        for (int k = 0; k < 20; ++k) {
            int i = i0 + k;
            filt[i][r] = sum;
            int add = i + 16, rem = i - 16;
            if (add <= D - 1) sum += ln[add];
            if (rem >= 0)     sum -= ln[rem];
        }
    }
    __syncthreads();

    int r = threadIdx.x & 31;
    for (int c = (threadIdx.x >> 5); c < D; c += 8)
        out[(size_t)c * DD + L0 + r] = filt[c][r];
}

// ---------------------------------------------------------------------------
// Rotate box filter, FLOAT path, pass 1: fuses the lsize*valid gather.
// fp order differs from reference cumsum: perturbs only proba (~1e-7 vs
// 2e-2 threshold); candidates are integer-exact.
// ---------------------------------------------------------------------------
__global__ __launch_bounds__(256) void box_rot_f32_g_kernel(
    const int* __restrict__ lab, const int* __restrict__ cnt,
    const unsigned* __restrict__ cwp, float* __restrict__ out)
{
    __shared__ float tin[32][161];
    __shared__ float filt[160][33];
    int L0 = blockIdx.x * 32;
    size_t base = (size_t)L0 * D;

    const int4*  lab4 = (const int4*)(lab + base);
    const uint4* cw4  = (const uint4*)(cwp + base);
    for (int i = threadIdx.x; i < 32 * (D / 4); i += 256) {
        int4 l = lab4[i];
        uint4 cw = cw4[i];
        int e = i * 4, r = e / D, c = e - r * D;
        tin[r][c]   = (l.x != BIGV && (cw.x >> 16) > 100u) ? (float)cnt[l.x] : 0.f;
        tin[r][c+1] = (l.y != BIGV && (cw.y >> 16) > 100u) ? (float)cnt[l.y] : 0.f;
        tin[r][c+2] = (l.z != BIGV && (cw.z >> 16) > 100u) ? (float)cnt[l.z] : 0.f;
        tin[r][c+3] = (l.w != BIGV && (cw.w >> 16) > 100u) ? (float)cnt[l.w] : 0.f;
    }
    __syncthreads();

    {
        int r = threadIdx.x & 31, s = threadIdx.x >> 5;
        int i0 = 20 * s;
        const float* ln = tin[r];
        float sum = 0.f;
        int jlo = i0 - 16; if (jlo < 0) jlo = 0;
        int jhi = i0 + 15; if (jhi > D - 1) jhi = D - 1;
        for (int j = jlo; j <= jhi; ++j) sum += ln[j];
        #pragma unroll 4
        for (int k = 0; k < 20; ++k) {
            int i = i0 + k;
            filt[i][r] = sum;
            int add = i + 16, rem = i - 16;
            if (add <= D - 1) sum += ln[add];
            if (rem >= 0)     sum -= ln[rem];
        }
    }
    __syncthreads();

    int r = threadIdx.x & 31;
    for (int c = (threadIdx.x >> 5); c < D; c += 8)
        out[(size_t)c * DD + L0 + r] = filt[c][r];
}

// plain float middle pass
__global__ __launch_bounds__(256) void box_rot_f32_kernel(
    const float* __restrict__ fin, float* __restrict__ out)
{
    __shared__ float tin[32][161];
    __shared__ float filt[160][33];
    int L0 = blockIdx.x * 32;
    size_t base = (size_t)L0 * D;

    const float4* s4 = (const float4*)(fin + base);
    for (int i = threadIdx.x; i < 32 * (D / 4); i += 256) {
        float4 v = s4[i];
        int e = i * 4, r = e / D, c = e - r * D;
        tin[r][c] = v.x; tin[r][c+1] = v.y; tin[r][c+2] = v.z; tin[r][c+3] = v.w;
    }
    __syncthreads();

    {
        int r = threadIdx.x & 31, s = threadIdx.x >> 5;
        int i0 = 20 * s;
        const float* ln = tin[r];
        float sum = 0.f;
        int jlo = i0 - 16; if (jlo < 0) jlo = 0;
        int jhi = i0 + 15; if (jhi > D - 1) jhi = D - 1;
        for (int j = jlo; j <= jhi; ++j) sum += ln[j];
        #pragma unroll 4
        for (int k = 0; k < 20; ++k) {
            int i = i0 + k;
            filt[i][r] = sum;
            int add = i + 16, rem = i - 16;
            if (add <= D - 1) sum += ln[add];
            if (rem >= 0)     sum -= ln[rem];
        }
    }
    __syncthreads();

    int r = threadIdx.x & 31;
    for (int c = (threadIdx.x >> 5); c < D; c += 8)
        out[(size_t)c * DD + L0 + r] = filt[c][r];
}

// ---------------------------------------------------------------------------
// cs pass 3 fused with finalize: filter along x; compute candidates / bin
// idx / LDS histogram directly (cs never materialized).
// Input layout (y,z,x): line L = y*D+z, elems along x. Output p = x*DD+L.
// ---------------------------------------------------------------------------
__global__ __launch_bounds__(256) void box_rot_fin_kernel(
    const float* __restrict__ fin, const unsigned* __restrict__ cwp,
    float* __restrict__ cand, unsigned short* __restrict__ idxbuf,
    int* __restrict__ partial)
{
    __shared__ float tin[32][161];
    __shared__ float filt[160][33];
    __shared__ int lh[NBINS];
    for (int i = threadIdx.x; i < NBINS; i += 256) lh[i] = 0;

    int L0 = blockIdx.x * 32;
    size_t base = (size_t)L0 * D;
    const float4* s4 = (const float4*)(fin + base);
    for (int i = threadIdx.x; i < 32 * (D / 4); i += 256) {
        float4 v = s4[i];
        int e = i * 4, r = e / D, c = e - r * D;
        tin[r][c] = v.x; tin[r][c+1] = v.y; tin[r][c+2] = v.z; tin[r][c+3] = v.w;
    }
    __syncthreads();

    {
        int r = threadIdx.x & 31, s = threadIdx.x >> 5;
        int i0 = 20 * s;
        const float* ln = tin[r];
        float sum = 0.f;
        int jlo = i0 - 16; if (jlo < 0) jlo = 0;
        int jhi = i0 + 15; if (jhi > D - 1) jhi = D - 1;
        for (int j = jlo; j <= jhi; ++j) sum += ln[j];
        #pragma unroll 4
        for (int k = 0; k < 20; ++k) {
            int i = i0 + k;
            filt[i][r] = sum;
            int add = i + 16, rem = i - 16;
            if (add <= D - 1) sum += ln[add];
            if (rem >= 0)     sum -= ln[rem];
        }
    }
    __syncthreads();

    int r = threadIdx.x & 31;
    int L = L0 + r;
    int y = L / D, z = L - (L / D) * D;
    bool byz = (y >= HALF && y < D - HALF && z >= HALF && z < D - HALF);
    int wy = min(y + 15, D - 1) - max(y - 16, 0) + 1;
    int wz = min(z + 15, D - 1) - max(z - 16, 0) + 1;
    for (int c = (threadIdx.x >> 5); c < D; c += 8) {   // c == x
        int p = c * DD + L;
        unsigned pk = cwp[p];
        unsigned cw0 = pk & 0xFFFFu;
        unsigned cw1 = pk >> 16;
        int wx = min(c + 15, D - 1) - max(c - 16, 0) + 1;
        unsigned cw2 = (unsigned)(wx * wy * wz) - cw0 - cw1;
        float v0 = (cw0 > 100u) ? 1.f : 0.f;
        float v1 = (cw1 > 100u) ? 1.f : 0.f;
        float v2 = (cw2 > 100u) ? 1.f : 0.f;
        float border = (byz && c >= HALF && c < D - HALF) ? 1.f : 0.f;
        float cd = (border * v1 + v0 + v2 >= 2.f) ? 1.f : 0.f;
        cand[p] = cd;
        float mean = (cw1 > 0u) ? filt[c][r] / fmaxf((float)cw1, 1.f) : 0.f;
        int idx = (int)rintf(cd * mean);    // round half-to-even == jnp.round
        idx = min(max(idx, 0), NBINS - 1);
        idxbuf[p] = (unsigned short)idx;
        if (idx != 0) atomicAdd(&lh[idx], 1);   // hist[0] never consumed
    }
    __syncthreads();
    int* po = partial + blockIdx.x * NBINS;
    for (int i = threadIdx.x; i < NBINS; i += 256) po[i] = lh[i];
}

// ---------------------------------------------------------------------------
// Flat CCL sweep, one launch per sweep. CPT=8 (two int4 quads) — the R6
// proven store pattern; CPT=16's 4x 64B-stride dwordx4 stores caused ~3x
// L2 sector writeback amplification (R8/R9/R10 all showed it).
// XCD swizzle kept from R10 (verified FETCH 28.9 -> 9.5 MB): each XCD gets
// a contiguous 20-plane x-slab (2 MB, L2-resident) so x+-1 plane reads and
// the previous generation's dst hit the local L2.
// ---------------------------------------------------------------------------
__device__ __forceinline__ int min6(int c, int a, int b, int d, int e, int f, int g) {
    if (c == BIGV) return BIGV;
    return min(min(min(c, a), min(b, d)), min(min(e, f), g));
}

__device__ __forceinline__ void wave_count(int l, int lane, int* __restrict__ cnt) {
    unsigned long long remaining = __ballot(l != BIGV);
    while (remaining) {
        int leader = __ffsll((unsigned long long)remaining) - 1;
        int ll = __shfl(l, leader, 64);
        unsigned long long mm = __ballot(l == ll);
        if (lane == leader) atomicAdd(&cnt[ll], (int)__popcll(mm & remaining));
        remaining &= ~mm;
    }
}

template<int COUNT>
__global__ __launch_bounds__(256) void ccl_sweep8_kernel(
    const int* __restrict__ lab, int* __restrict__ outp, int* __restrict__ cnt)
{
    int b = blockIdx.x;                          // 0..1999
    int sb = (b & 7) * (SGRID / 8) + (b >> 3);   // XCD-contiguous x-slab
    int t = sb * 256 + threadIdx.x;
    int p = t * 8;
    int q = t * 2;
    const int4* lab4 = (const int4*)lab;
    int4 c0 = lab4[q], c1 = lab4[q + 1];

    int z0 = p % D;                              // multiple of 8
    int lane = threadIdx.x & 63;
    int lm = __shfl_up(c1.w, 1);                 // lab[p-1]
    int rm = __shfl_down(c0.x, 1);               // lab[p+8]
    if (z0 == 0)          lm = BIGV;
    else if (lane == 0)   lm = lab[p - 1];
    if (z0 == D - 8)      rm = BIGV;
    else if (lane == 63)  rm = lab[p + 8];

    int r = p / D;
    int y = r % D;
    int x = r / D;
    const int4 BIG4 = make_int4(BIGV, BIGV, BIGV, BIGV);
    int4 yl0 = BIG4, yl1 = BIG4, yh0 = BIG4, yh1 = BIG4;
    int4 xl0 = BIG4, xl1 = BIG4, xh0 = BIG4, xh1 = BIG4;
    if (y > 0)     { yl0 = lab4[q - D/4];     yl1 = lab4[q - D/4 + 1]; }
    if (y < D - 1) { yh0 = lab4[q + D/4];     yh1 = lab4[q + D/4 + 1]; }
    if (x > 0)     { xl0 = lab4[q - DD/4];    xl1 = lab4[q - DD/4 + 1]; }
    if (x < D - 1) { xh0 = lab4[q + DD/4];    xh1 = lab4[q + DD/4 + 1]; }

    int4 o0, o1;
    o0.x = min6(c0.x, lm,   c0.y, yl0.x, yh0.x, xl0.x, xh0.x);
    o0.y = min6(c0.y, c0.x, c0.z, yl0.y, yh0.y, xl0.y, xh0.y);
    o0.z = min6(c0.z, c0.y, c0.w, yl0.z, yh0.z, xl0.z, xh0.z);
    o0.w = min6(c0.w, c0.z, c1.x, yl0.w, yh0.w, xl0.w, xh0.w);
    o1.x = min6(c1.x, c0.w, c1.y, yl1.x, yh1.x, xl1.x, xh1.x);
    o1.y = min6(c1.y, c1.x, c1.z, yl1.y, yh1.y, xl1.y, xh1.y);
    o1.z = min6(c1.z, c1.y, c1.w, yl1.z, yh1.z, xl1.z, xh1.z);
    o1.w = min6(c1.w, c1.z, rm,   yl1.w, yh1.w, xl1.w, xh1.w);

    int4* out4 = (int4*)outp;
    out4[q] = o0; out4[q + 1] = o1;

    if (COUNT) {   // final sweep: component-size count from registers
        wave_count(o0.x, lane, cnt);
        wave_count(o0.y, lane, cnt);
        wave_count(o0.z, lane, cnt);
        wave_count(o0.w, lane, cnt);
        wave_count(o1.x, lane, cnt);
        wave_count(o1.y, lane, cnt);
        wave_count(o1.z, lane, cnt);
        wave_count(o1.w, lane, cnt);
    }
}

// ---------------------------------------------------------------------------
// hist[bin] = sum over RGRID block partials (coalesced, L2-resident)
// ---------------------------------------------------------------------------
__global__ __launch_bounds__(256) void hist_reduce_kernel(
    const int* __restrict__ partial, int* __restrict__ hist)
{
    int bin = blockIdx.x * 256 + threadIdx.x;   // 16 x 256 = 4096
    int s = 0;
    #pragma unroll 4
    for (int b = 0; b < RGRID; ++b) s += partial[b * NBINS + bin];
    hist[bin] = s;
}

// ---------------------------------------------------------------------------
// histogram post-processing: rec -> ph_full (normalized), S = sum hist*ph.
// Guards (sumrec>0, S>0) degrade an all-zero histogram to 0 instead of NaN.
// ---------------------------------------------------------------------------
__global__ __launch_bounds__(256) void hist_post_kernel(
    const int* __restrict__ hist, float* __restrict__ ph_full,
    float* __restrict__ Sout)
{
    __shared__ float red[256];
    int t = threadIdx.x;

    float loc = 0.f;
    for (int b = t; b < NBINS; b += 256)
        if (b >= 1) loc += (float)hist[b];
    red[t] = loc; __syncthreads();
    for (int o = 128; o > 0; o >>= 1) { if (t < o) red[t] += red[t + o]; __syncthreads(); }
    float numb = red[0]; __syncthreads();

    loc = 0.f;
    for (int b = t; b < NBINS; b += 256) {
        float r = 0.f;
        if (b >= 1) {
            int h = hist[b];
            if (h > 0) r = numb / (float)h;
        }
        ph_full[b] = r;
        loc += r;
    }
    red[t] = loc; __syncthreads();
    for (int o = 128; o > 0; o >>= 1) { if (t < o) red[t] += red[t + o]; __syncthreads(); }
    float sumrec = red[0]; __syncthreads();
    float inv_sumrec = (sumrec > 0.f) ? 1.f / sumrec : 0.f;

    loc = 0.f;
    for (int b = t; b < NBINS; b += 256) {
        float ph = (b >= 1) ? ph_full[b] * inv_sumrec : 0.f;
        ph_full[b] = ph;
        loc += ph * (float)hist[b];
    }
    red[t] = loc; __syncthreads();
    for (int o = 128; o > 0; o >>= 1) { if (t < o) red[t] += red[t + o]; __syncthreads(); }
    if (t == 0) Sout[0] = (red[0] > 0.f) ? red[0] : 1.f;
}

__global__ __launch_bounds__(256) void proba_kernel(
    const unsigned short* __restrict__ idxbuf,
    const float* __restrict__ ph_full, const float* __restrict__ Sv,
    float* __restrict__ outp)
{
    int p = blockIdx.x * blockDim.x + threadIdx.x;   // exact grid
    outp[p] = ph_full[idxbuf[p]] / Sv[0];
}

// ---------------------------------------------------------------------------
extern "C" void kernel_launch(void* const* d_in, const int* in_sizes, int n_in,
                              void* d_out, int out_size, void* d_ws, size_t ws_size,
                              hipStream_t stream)
{
    const float* data = (const float*)d_in[0];
    float* out   = (float*)d_out;
    float* cand  = out;
    float* proba = out + NVOX;

    char* ws = (char*)d_ws;
    const size_t NB = (size_t)NVOX * sizeof(float);
    float* W1 = (float*)(ws);
    float* W2 = (float*)(ws + NB);
    float* W3 = (float*)(ws + 2 * NB);
    int*   cnt  = (int*)(ws + 3 * NB);                 // NVOX+1 ints
    float* ph   = (float*)(ws + 4 * NB + 16);
    int*   hist = (int*)  (ws + 4 * NB + 16 + NBINS * 4);
    float* Sv   = (float*)(ws + 4 * NB + 16 + 2 * NBINS * 4);
    unsigned short* idxbuf = (unsigned short*)cnt;     // cnt dead after cs pass 1
    int* partial = (int*)W3;                           // W3 dead after cs pass 2

    dim3 eb(256), eg(NVOX / 256);          // 16000 blocks (proba)
    dim3 rb(256), rg(RGRID);               // 800 blocks (rotate passes)
    dim3 sbk(256), sg(SGRID);              // 2000 blocks (sweeps)

    hipMemsetAsync(cnt, 0, (NVOX + 1) * sizeof(int), stream);

    // cw packed box sums via rotate pipeline (pass 1 fuses pack + lab init)
    box_rot_int_kernel<0><<<rg, rb, 0, stream>>>(data, (unsigned*)W1, (int*)W2);
    box_rot_int_kernel<1><<<rg, rb, 0, stream>>>(W1, (unsigned*)W3, nullptr);
    box_rot_int_kernel<1><<<rg, rb, 0, stream>>>(W3, (unsigned*)W1, nullptr);
    unsigned* cwp = (unsigned*)W1;         // original layout

    // CCL: 16 flat synchronous sweeps, ping-pong W2 <-> W3;
    // sweep 16 fuses the component-size count (labels already in registers)
    for (int s = 0; s < NSWEEP - 1; ++s) {
        const int* src = (s & 1) ? (int*)W3 : (int*)W2;
        int*       dst = (s & 1) ? (int*)W2 : (int*)W3;
        ccl_sweep8_kernel<0><<<sg, sbk, 0, stream>>>(src, dst, nullptr);
    }
    ccl_sweep8_kernel<1><<<sg, sbk, 0, stream>>>((int*)W3, (int*)W2, cnt);
    int* lab = (int*)W2;

    // cs float box sums (pass 1 fuses lsize*valid gather; pass 3 fuses
    // finalize: cand + idx + histogram — cs never materialized)
    box_rot_f32_g_kernel<<<rg, rb, 0, stream>>>(lab, cnt, cwp, W3);
    box_rot_f32_kernel<<<rg, rb, 0, stream>>>(W3, W2);
    box_rot_fin_kernel<<<rg, rb, 0, stream>>>(W2, cwp, cand, idxbuf, partial);

    hist_reduce_kernel<<<dim3(16), dim3(256), 0, stream>>>(partial, hist);
    hist_post_kernel<<<1, 256, 0, stream>>>(hist, ph, Sv);
    proba_kernel<<<eg, eb, 0, stream>>>(idxbuf, ph, Sv, proba);
}

// Round 12
// 422.448 us; speedup vs baseline: 11.6081x; 1.0097x over previous
//
#include <hip/hip_runtime.h>
#include <cmath>

#define D 160
#define DD (D*D)          // 25600
#define NVOX (D*D*D)
#define BIGV (NVOX + 2)
#define NBINS 4096
#define HALF 16
#define RGRID 800         // rotate-pass blocks = DD/32, also hist partial count
#define SGRID 1000        // sweep blocks (512 thr, 8 cells/thread)
#define NSWEEP 16

// ---------------------------------------------------------------------------
// Rotate-pipeline box filter (window 32, 'same'), INT packed path.
// Buffer layout (a,b,c) c-contiguous; filter along c; write out[c*DD+a*D+b]
// -> layout (c,a,b). Three passes return to identity with each axis filtered.
// MODE 0 packs classes from raw data (lab init no longer materialized —
// sweep 1 classifies data directly). cw0 low 16 bits, cw1 high 16.
// ---------------------------------------------------------------------------
template<int MODE>
__global__ __launch_bounds__(256) void box_rot_int_kernel(
    const void* __restrict__ vin, unsigned* __restrict__ out)
{
    __shared__ unsigned tin[32][161];
    __shared__ unsigned filt[160][33];
    int L0 = blockIdx.x * 32;
    size_t base = (size_t)L0 * D;

    if (MODE == 0) {
        const float4* s4 = (const float4*)((const float*)vin + base);
        for (int i = threadIdx.x; i < 32 * (D / 4); i += 256) {
            float4 v = s4[i];
            int e = i * 4, r = e / D, c = e - r * D;
            float rr;
            rr = rintf(v.x); tin[r][c]   = (rr==0.f) | ((rr==1.f)?0x10000u:0u);
            rr = rintf(v.y); tin[r][c+1] = (rr==0.f) | ((rr==1.f)?0x10000u:0u);
            rr = rintf(v.z); tin[r][c+2] = (rr==0.f) | ((rr==1.f)?0x10000u:0u);
            rr = rintf(v.w); tin[r][c+3] = (rr==0.f) | ((rr==1.f)?0x10000u:0u);
        }
    } else {
        const uint4* s4 = (const uint4*)((const unsigned*)vin + base);
        for (int i = threadIdx.x; i < 32 * (D / 4); i += 256) {
            uint4 v = s4[i];
            int e = i * 4, r = e / D, c = e - r * D;
            tin[r][c] = v.x; tin[r][c+1] = v.y; tin[r][c+2] = v.z; tin[r][c+3] = v.w;
        }
    }
    __syncthreads();

    {
        int r = threadIdx.x & 31, s = threadIdx.x >> 5;
        int i0 = 20 * s;
        const unsigned* ln = tin[r];
        unsigned sum = 0u;
        int jlo = i0 - 16; if (jlo < 0) jlo = 0;
        int jhi = i0 + 15; if (jhi > D - 1) jhi = D - 1;
        for (int j = jlo; j <= jhi; ++j) sum += ln[j];
        #pragma unroll 4
        for (int k = 0; k < 20; ++k) {
            int i = i0 + k;
            filt[i][r] = sum;
            int add = i + 16, rem = i - 16;
            if (add <= D - 1) sum += ln[add];
            if (rem >= 0)     sum -= ln[rem];
        }
    }
    __syncthreads();

    int r = threadIdx.x & 31;
    for (int c = (threadIdx.x >> 5); c < D; c += 8)
        out[(size_t)c * DD + L0 + r] = filt[c][r];
}

// ---------------------------------------------------------------------------
// Rotate box filter, FLOAT path, pass 1: fuses the lsize*valid gather.
// fp order differs from reference cumsum: perturbs only proba (~1e-7 vs
// 2e-2 threshold); candidates are integer-exact.
// ---------------------------------------------------------------------------
__global__ __launch_bounds__(256) void box_rot_f32_g_kernel(
    const int* __restrict__ lab, const int* __restrict__ cnt,
    const unsigned* __restrict__ cwp, float* __restrict__ out)
{
    __shared__ float tin[32][161];
    __shared__ float filt[160][33];
    int L0 = blockIdx.x * 32;
    size_t base = (size_t)L0 * D;

    const int4*  lab4 = (const int4*)(lab + base);
    const uint4* cw4  = (const uint4*)(cwp + base);
    for (int i = threadIdx.x; i < 32 * (D / 4); i += 256) {
        int4 l = lab4[i];
        uint4 cw = cw4[i];
        int e = i * 4, r = e / D, c = e - r * D;
        tin[r][c]   = (l.x != BIGV && (cw.x >> 16) > 100u) ? (float)cnt[l.x] : 0.f;
        tin[r][c+1] = (l.y != BIGV && (cw.y >> 16) > 100u) ? (float)cnt[l.y] : 0.f;
        tin[r][c+2] = (l.z != BIGV && (cw.z >> 16) > 100u) ? (float)cnt[l.z] : 0.f;
        tin[r][c+3] = (l.w != BIGV && (cw.w >> 16) > 100u) ? (float)cnt[l.w] : 0.f;
    }
    __syncthreads();

    {
        int r = threadIdx.x & 31, s = threadIdx.x >> 5;
        int i0 = 20 * s;
        const float* ln = tin[r];
        float sum = 0.f;
        int jlo = i0 - 16; if (jlo < 0) jlo = 0;
        int jhi = i0 + 15; if (jhi > D - 1) jhi = D - 1;
        for (int j = jlo; j <= jhi; ++j) sum += ln[j];
        #pragma unroll 4
        for (int k = 0; k < 20; ++k) {
            int i = i0 + k;
            filt[i][r] = sum;
            int add = i + 16, rem = i - 16;
            if (add <= D - 1) sum += ln[add];
            if (rem >= 0)     sum -= ln[rem];
        }
    }
    __syncthreads();

    int r = threadIdx.x & 31;
    for (int c = (threadIdx.x >> 5); c < D; c += 8)
        out[(size_t)c * DD + L0 + r] = filt[c][r];
}

// plain float middle pass
__global__ __launch_bounds__(256) void box_rot_f32_kernel(
    const float* __restrict__ fin, float* __restrict__ out)
{
    __shared__ float tin[32][161];
    __shared__ float filt[160][33];
    int L0 = blockIdx.x * 32;
    size_t base = (size_t)L0 * D;

    const float4* s4 = (const float4*)(fin + base);
    for (int i = threadIdx.x; i < 32 * (D / 4); i += 256) {
        float4 v = s4[i];
        int e = i * 4, r = e / D, c = e - r * D;
        tin[r][c] = v.x; tin[r][c+1] = v.y; tin[r][c+2] = v.z; tin[r][c+3] = v.w;
    }
    __syncthreads();

    {
        int r = threadIdx.x & 31, s = threadIdx.x >> 5;
        int i0 = 20 * s;
        const float* ln = tin[r];
        float sum = 0.f;
        int jlo = i0 - 16; if (jlo < 0) jlo = 0;
        int jhi = i0 + 15; if (jhi > D - 1) jhi = D - 1;
        for (int j = jlo; j <= jhi; ++j) sum += ln[j];
        #pragma unroll 4
        for (int k = 0; k < 20; ++k) {
            int i = i0 + k;
            filt[i][r] = sum;
            int add = i + 16, rem = i - 16;
            if (add <= D - 1) sum += ln[add];
            if (rem >= 0)     sum -= ln[rem];
        }
    }
    __syncthreads();

    int r = threadIdx.x & 31;
    for (int c = (threadIdx.x >> 5); c < D; c += 8)
        out[(size_t)c * DD + L0 + r] = filt[c][r];
}

// ---------------------------------------------------------------------------
// cs pass 3 fused with finalize: filter along x; compute candidates / bin
// idx / LDS histogram directly (cs never materialized).
// Input layout (y,z,x): line L = y*D+z, elems along x. Output p = x*DD+L.
// ---------------------------------------------------------------------------
__global__ __launch_bounds__(256) void box_rot_fin_kernel(
    const float* __restrict__ fin, const unsigned* __restrict__ cwp,
    float* __restrict__ cand, unsigned short* __restrict__ idxbuf,
    int* __restrict__ partial)
{
    __shared__ float tin[32][161];
    __shared__ float filt[160][33];
    __shared__ int lh[NBINS];
    for (int i = threadIdx.x; i < NBINS; i += 256) lh[i] = 0;

    int L0 = blockIdx.x * 32;
    size_t base = (size_t)L0 * D;
    const float4* s4 = (const float4*)(fin + base);
    for (int i = threadIdx.x; i < 32 * (D / 4); i += 256) {
        float4 v = s4[i];
        int e = i * 4, r = e / D, c = e - r * D;
        tin[r][c] = v.x; tin[r][c+1] = v.y; tin[r][c+2] = v.z; tin[r][c+3] = v.w;
    }
    __syncthreads();

    {
        int r = threadIdx.x & 31, s = threadIdx.x >> 5;
        int i0 = 20 * s;
        const float* ln = tin[r];
        float sum = 0.f;
        int jlo = i0 - 16; if (jlo < 0) jlo = 0;
        int jhi = i0 + 15; if (jhi > D - 1) jhi = D - 1;
        for (int j = jlo; j <= jhi; ++j) sum += ln[j];
        #pragma unroll 4
        for (int k = 0; k < 20; ++k) {
            int i = i0 + k;
            filt[i][r] = sum;
            int add = i + 16, rem = i - 16;
            if (add <= D - 1) sum += ln[add];
            if (rem >= 0)     sum -= ln[rem];
        }
    }
    __syncthreads();

    int r = threadIdx.x & 31;
    int L = L0 + r;
    int y = L / D, z = L - (L / D) * D;
    bool byz = (y >= HALF && y < D - HALF && z >= HALF && z < D - HALF);
    int wy = min(y + 15, D - 1) - max(y - 16, 0) + 1;
    int wz = min(z + 15, D - 1) - max(z - 16, 0) + 1;
    for (int c = (threadIdx.x >> 5); c < D; c += 8) {   // c == x
        int p = c * DD + L;
        unsigned pk = cwp[p];
        unsigned cw0 = pk & 0xFFFFu;
        unsigned cw1 = pk >> 16;
        int wx = min(c + 15, D - 1) - max(c - 16, 0) + 1;
        unsigned cw2 = (unsigned)(wx * wy * wz) - cw0 - cw1;
        float v0 = (cw0 > 100u) ? 1.f : 0.f;
        float v1 = (cw1 > 100u) ? 1.f : 0.f;
        float v2 = (cw2 > 100u) ? 1.f : 0.f;
        float border = (byz && c >= HALF && c < D - HALF) ? 1.f : 0.f;
        float cd = (border * v1 + v0 + v2 >= 2.f) ? 1.f : 0.f;
        cand[p] = cd;
        float mean = (cw1 > 0u) ? filt[c][r] / fmaxf((float)cw1, 1.f) : 0.f;
        int idx = (int)rintf(cd * mean);    // round half-to-even == jnp.round
        idx = min(max(idx, 0), NBINS - 1);
        idxbuf[p] = (unsigned short)idx;
        if (idx != 0) atomicAdd(&lh[idx], 1);   // hist[0] never consumed
    }
    __syncthreads();
    int* po = partial + blockIdx.x * NBINS;
    for (int i = threadIdx.x; i < NBINS; i += 256) po[i] = lh[i];
}

// ---------------------------------------------------------------------------
// Flat CCL sweeps, one launch per sweep (cheapest generation boundary
// measured: grid.sync ~280us/gen (R8), flag-spin ~270us/gen (R9), LDS halo
// fusion 55us/2gen (R5) — all lose to ~9-12us kernel-launch sync).
// CPT=8 (two int4 quads: the merge-friendly store pattern; CPT=16's 64B-
// stride stores cost 3x L2 sector-writeback amplification, R10).
// XCD swizzle: each XCD owns a contiguous 20-plane x-slab (2 MB, L2-
// resident): verified FETCH 28.9 -> 9.1 MB/sweep.
// Sweep 1 classifies raw data inline (no materialized lab-init buffer).
// ---------------------------------------------------------------------------
__device__ __forceinline__ int min6(int c, int a, int b, int d, int e, int f, int g) {
    if (c == BIGV) return BIGV;
    return min(min(min(c, a), min(b, d)), min(min(e, f), g));
}

__device__ __forceinline__ void wave_count(int l, int lane, int* __restrict__ cnt) {
    unsigned long long remaining = __ballot(l != BIGV);
    while (remaining) {
        int leader = __ffsll((unsigned long long)remaining) - 1;
        int ll = __shfl(l, leader, 64);
        unsigned long long mm = __ballot(l == ll);
        if (lane == leader) atomicAdd(&cnt[ll], (int)__popcll(mm & remaining));
        remaining &= ~mm;
    }
}

__device__ __forceinline__ int4 cls4(float4 v, int p0) {
    int4 l;
    l.x = (rintf(v.x) == 1.f) ? (p0 + 1) : BIGV;
    l.y = (rintf(v.y) == 1.f) ? (p0 + 2) : BIGV;
    l.z = (rintf(v.z) == 1.f) ? (p0 + 3) : BIGV;
    l.w = (rintf(v.w) == 1.f) ? (p0 + 4) : BIGV;
    return l;
}

// sweep 1: gen-1 labels straight from data (lab0 derived, never stored)
__global__ __launch_bounds__(512) void ccl_sweep1_data_kernel(
    const float* __restrict__ data, int* __restrict__ outp)
{
    int b = blockIdx.x;                          // 0..999
    int sb = (b & 7) * (SGRID / 8) + (b >> 3);   // XCD-contiguous x-slab
    int t = sb * 512 + threadIdx.x;
    int p = t * 8;
    int q = t * 2;
    const float4* d4 = (const float4*)data;
    int4 c0 = cls4(d4[q], p), c1 = cls4(d4[q + 1], p + 4);

    int z0 = p % D;
    int lane = threadIdx.x & 63;
    int lm = __shfl_up(c1.w, 1);
    int rm = __shfl_down(c0.x, 1);
    if (z0 == 0)          lm = BIGV;
    else if (lane == 0)   lm = (rintf(data[p - 1]) == 1.f) ? p : BIGV;
    if (z0 == D - 8)      rm = BIGV;
    else if (lane == 63)  rm = (rintf(data[p + 8]) == 1.f) ? (p + 9) : BIGV;

    int r = p / D;
    int y = r % D;
    int x = r / D;
    const int4 BIG4 = make_int4(BIGV, BIGV, BIGV, BIGV);
    int4 yl0 = BIG4, yl1 = BIG4, yh0 = BIG4, yh1 = BIG4;
    int4 xl0 = BIG4, xl1 = BIG4, xh0 = BIG4, xh1 = BIG4;
    if (y > 0)     { yl0 = cls4(d4[q - D/4], p - D);      yl1 = cls4(d4[q - D/4 + 1], p - D + 4); }
    if (y < D - 1) { yh0 = cls4(d4[q + D/4], p + D);      yh1 = cls4(d4[q + D/4 + 1], p + D + 4); }
    if (x > 0)     { xl0 = cls4(d4[q - DD/4], p - DD);    xl1 = cls4(d4[q - DD/4 + 1], p - DD + 4); }
    if (x < D - 1) { xh0 = cls4(d4[q + DD/4], p + DD);    xh1 = cls4(d4[q + DD/4 + 1], p + DD + 4); }

    int4 o0, o1;
    o0.x = min6(c0.x, lm,   c0.y, yl0.x, yh0.x, xl0.x, xh0.x);
    o0.y = min6(c0.y, c0.x, c0.z, yl0.y, yh0.y, xl0.y, xh0.y);
    o0.z = min6(c0.z, c0.y, c0.w, yl0.z, yh0.z, xl0.z, xh0.z);
    o0.w = min6(c0.w, c0.z, c1.x, yl0.w, yh0.w, xl0.w, xh0.w);
    o1.x = min6(c1.x, c0.w, c1.y, yl1.x, yh1.x, xl1.x, xh1.x);
    o1.y = min6(c1.y, c1.x, c1.z, yl1.y, yh1.y, xl1.y, xh1.y);
    o1.z = min6(c1.z, c1.y, c1.w, yl1.z, yh1.z, xl1.z, xh1.z);
    o1.w = min6(c1.w, c1.z, rm,   yl1.w, yh1.w, xl1.w, xh1.w);

    int4* out4 = (int4*)outp;
    out4[q] = o0; out4[q + 1] = o1;
}

template<int COUNT>
__global__ __launch_bounds__(512) void ccl_sweep8_kernel(
    const int* __restrict__ lab, int* __restrict__ outp, int* __restrict__ cnt)
{
    int b = blockIdx.x;                          // 0..999
    int sb = (b & 7) * (SGRID / 8) + (b >> 3);   // XCD-contiguous x-slab
    int t = sb * 512 + threadIdx.x;
    int p = t * 8;
    int q = t * 2;
    const int4* lab4 = (const int4*)lab;
    int4 c0 = lab4[q], c1 = lab4[q + 1];

    int z0 = p % D;
    int lane = threadIdx.x & 63;
    int lm = __shfl_up(c1.w, 1);
    int rm = __shfl_down(c0.x, 1);
    if (z0 == 0)          lm = BIGV;
    else if (lane == 0)   lm = lab[p - 1];
    if (z0 == D - 8)      rm = BIGV;
    else if (lane == 63)  rm = lab[p + 8];

    int r = p / D;
    int y = r % D;
    int x = r / D;
    const int4 BIG4 = make_int4(BIGV, BIGV, BIGV, BIGV);
    int4 yl0 = BIG4, yl1 = BIG4, yh0 = BIG4, yh1 = BIG4;
    int4 xl0 = BIG4, xl1 = BIG4, xh0 = BIG4, xh1 = BIG4;
    if (y > 0)     { yl0 = lab4[q - D/4];     yl1 = lab4[q - D/4 + 1]; }
    if (y < D - 1) { yh0 = lab4[q + D/4];     yh1 = lab4[q + D/4 + 1]; }
    if (x > 0)     { xl0 = lab4[q - DD/4];    xl1 = lab4[q - DD/4 + 1]; }
    if (x < D - 1) { xh0 = lab4[q + DD/4];    xh1 = lab4[q + DD/4 + 1]; }

    int4 o0, o1;
    o0.x = min6(c0.x, lm,   c0.y, yl0.x, yh0.x, xl0.x, xh0.x);
    o0.y = min6(c0.y, c0.x, c0.z, yl0.y, yh0.y, xl0.y, xh0.y);
    o0.z = min6(c0.z, c0.y, c0.w, yl0.z, yh0.z, xl0.z, xh0.z);
    o0.w = min6(c0.w, c0.z, c1.x, yl0.w, yh0.w, xl0.w, xh0.w);
    o1.x = min6(c1.x, c0.w, c1.y, yl1.x, yh1.x, xl1.x, xh1.x);
    o1.y = min6(c1.y, c1.x, c1.z, yl1.y, yh1.y, xl1.y, xh1.y);
    o1.z = min6(c1.z, c1.y, c1.w, yl1.z, yh1.z, xl1.z, xh1.z);
    o1.w = min6(c1.w, c1.z, rm,   yl1.w, yh1.w, xl1.w, xh1.w);

    int4* out4 = (int4*)outp;
    out4[q] = o0; out4[q + 1] = o1;

    if (COUNT) {   // final sweep: component-size count from registers
        wave_count(o0.x, lane, cnt);
        wave_count(o0.y, lane, cnt);
        wave_count(o0.z, lane, cnt);
        wave_count(o0.w, lane, cnt);
        wave_count(o1.x, lane, cnt);
        wave_count(o1.y, lane, cnt);
        wave_count(o1.z, lane, cnt);
        wave_count(o1.w, lane, cnt);
    }
}

// ---------------------------------------------------------------------------
// hist[bin] = sum over RGRID block partials (coalesced, L2-resident)
// ---------------------------------------------------------------------------
__global__ __launch_bounds__(256) void hist_reduce_kernel(
    const int* __restrict__ partial, int* __restrict__ hist)
{
    int bin = blockIdx.x * 256 + threadIdx.x;   // 16 x 256 = 4096
    int s = 0;
    #pragma unroll 4
    for (int b = 0; b < RGRID; ++b) s += partial[b * NBINS + bin];
    hist[bin] = s;
}

// ---------------------------------------------------------------------------
// histogram post-processing: rec -> ph_full (normalized), S = sum hist*ph.
// Guards (sumrec>0, S>0) degrade an all-zero histogram to 0 instead of NaN.
// ---------------------------------------------------------------------------
__global__ __launch_bounds__(256) void hist_post_kernel(
    const int* __restrict__ hist, float* __restrict__ ph_full,
    float* __restrict__ Sout)
{
    __shared__ float red[256];
    int t = threadIdx.x;

    float loc = 0.f;
    for (int b = t; b < NBINS; b += 256)
        if (b >= 1) loc += (float)hist[b];
    red[t] = loc; __syncthreads();
    for (int o = 128; o > 0; o >>= 1) { if (t < o) red[t] += red[t + o]; __syncthreads(); }
    float numb = red[0]; __syncthreads();

    loc = 0.f;
    for (int b = t; b < NBINS; b += 256) {
        float r = 0.f;
        if (b >= 1) {
            int h = hist[b];
            if (h > 0) r = numb / (float)h;
        }
        ph_full[b] = r;
        loc += r;
    }
    red[t] = loc; __syncthreads();
    for (int o = 128; o > 0; o >>= 1) { if (t < o) red[t] += red[t + o]; __syncthreads(); }
    float sumrec = red[0]; __syncthreads();
    float inv_sumrec = (sumrec > 0.f) ? 1.f / sumrec : 0.f;

    loc = 0.f;
    for (int b = t; b < NBINS; b += 256) {
        float ph = (b >= 1) ? ph_full[b] * inv_sumrec : 0.f;
        ph_full[b] = ph;
        loc += ph * (float)hist[b];
    }
    red[t] = loc; __syncthreads();
    for (int o = 128; o > 0; o >>= 1) { if (t < o) red[t] += red[t + o]; __syncthreads(); }
    if (t == 0) Sout[0] = (red[0] > 0.f) ? red[0] : 1.f;
}

__global__ __launch_bounds__(256) void proba_kernel(
    const unsigned short* __restrict__ idxbuf,
    const float* __restrict__ ph_full, const float* __restrict__ Sv,
    float* __restrict__ outp)
{
    int t = blockIdx.x * blockDim.x + threadIdx.x;   // exact grid NVOX/4
    ushort4 i4 = ((const ushort4*)idxbuf)[t];
    float inv = 1.f / Sv[0];
    float4 o;
    o.x = ph_full[i4.x] * inv;
    o.y = ph_full[i4.y] * inv;
    o.z = ph_full[i4.z] * inv;
    o.w = ph_full[i4.w] * inv;
    ((float4*)outp)[t] = o;
}

// ---------------------------------------------------------------------------
extern "C" void kernel_launch(void* const* d_in, const int* in_sizes, int n_in,
                              void* d_out, int out_size, void* d_ws, size_t ws_size,
                              hipStream_t stream)
{
    const float* data = (const float*)d_in[0];
    float* out   = (float*)d_out;
    float* cand  = out;
    float* proba = out + NVOX;

    char* ws = (char*)d_ws;
    const size_t NB = (size_t)NVOX * sizeof(float);
    float* W1 = (float*)(ws);
    float* W2 = (float*)(ws + NB);
    float* W3 = (float*)(ws + 2 * NB);
    int*   cnt  = (int*)(ws + 3 * NB);                 // NVOX+1 ints
    float* ph   = (float*)(ws + 4 * NB + 16);
    int*   hist = (int*)  (ws + 4 * NB + 16 + NBINS * 4);
    float* Sv   = (float*)(ws + 4 * NB + 16 + 2 * NBINS * 4);
    unsigned short* idxbuf = (unsigned short*)cnt;     // cnt dead after cs pass 1
    int* partial = (int*)W2;                           // W2 dead after cs pass 2

    dim3 rb(256), rg(RGRID);               // 800 blocks (rotate passes)
    dim3 sbk(512), sg(SGRID);              // 1000 blocks (sweeps)
    dim3 pb(256), pg(NVOX / 4 / 256);      // 4000 blocks (proba x4)

    hipMemsetAsync(cnt, 0, (NVOX + 1) * sizeof(int), stream);

    // cw packed box sums via rotate pipeline (pass 1 packs classes; the
    // CCL lab-init buffer is no longer materialized)
    box_rot_int_kernel<0><<<rg, rb, 0, stream>>>(data, (unsigned*)W1);
    box_rot_int_kernel<1><<<rg, rb, 0, stream>>>(W1, (unsigned*)W3);
    box_rot_int_kernel<1><<<rg, rb, 0, stream>>>(W3, (unsigned*)W1);
    unsigned* cwp = (unsigned*)W1;         // original layout

    // CCL: sweep 1 from data; sweeps 2..15 ping-pong; sweep 16 fuses the
    // component-size count. gen1->W2; even gens->W3, odd->W2; gen16->W3.
    ccl_sweep1_data_kernel<<<sg, sbk, 0, stream>>>(data, (int*)W2);
    for (int i = 0; i < NSWEEP - 2; ++i) {             // sweeps 2..15
        const int* src = (i & 1) ? (int*)W3 : (int*)W2;
        int*       dst = (i & 1) ? (int*)W2 : (int*)W3;
        ccl_sweep8_kernel<0><<<sg, sbk, 0, stream>>>(src, dst, nullptr);
    }
    ccl_sweep8_kernel<1><<<sg, sbk, 0, stream>>>((int*)W2, (int*)W3, cnt);
    int* lab = (int*)W3;                   // gen-16 labels

    // cs float box sums (pass 1 fuses lsize*valid gather; pass 3 fuses
    // finalize: cand + idx + histogram — cs never materialized)
    box_rot_f32_g_kernel<<<rg, rb, 0, stream>>>(lab, cnt, cwp, W2);
    box_rot_f32_kernel<<<rg, rb, 0, stream>>>(W2, W3);
    box_rot_fin_kernel<<<rg, rb, 0, stream>>>(W3, cwp, cand, idxbuf, partial);

    hist_reduce_kernel<<<dim3(16), dim3(256), 0, stream>>>(partial, hist);
    hist_post_kernel<<<1, 256, 0, stream>>>(hist, ph, Sv);
    proba_kernel<<<pg, pb, 0, stream>>>(idxbuf, ph, Sv, proba);
}